// Round 13
// baseline (180.068 us; speedup 1.0000x reference)
//
#include <hip/hip_runtime.h>
#include <cstdint>
#include <cstddef>

// Problem constants (B=32, D=256, H=32, W=32, K=1024), N = B*H*W = 32768.
// MFMA path: fp32 -> 3x bf16 split; 6 concat-K segments -> bf16 GEMM
// M=32768 N=1024 K=1536; error ~ fp32 accumulation (numpy-grade).
//
// History: r9 = 256²/8-wave/4-phase/8-barriers-per-tile, 114.9µs GEMM,
// MfmaUtil 38%, 124 VGPR + 128 AGPR = 252/256 unified-reg KNIFE EDGE.
// r10/r11/r12 all spilled: any live-range growth exceeds the 256 cap
// because acc[8][4] alone is 128 AGPR. r13: per-wave tile 64x64 ->
// acc[4][4] = 64 AGPR, block tile 256x128 (8 waves = 4wr x 2wc). Headroom
// (~170/256) buys ONE fat phase per K-tile: {16 ds_read + 6 gl2lds(t+2) +
// 32 MFMA + vmcnt(6) + s_barrier} -- 1 barrier/tile vs r9's 8, 3-buffer
// LDS (144KB), prefetch window ~1 fat phase (~2000cyc) > HBM latency.
// Accumulation K-order per element unchanged -> bit-identical distances.

typedef __attribute__((ext_vector_type(8))) short bf16x8;
typedef __attribute__((ext_vector_type(4))) float f32x4;

#define GL2LDS(g, l) __builtin_amdgcn_global_load_lds( \
    (__attribute__((address_space(1))) const void*)(g), \
    (__attribute__((address_space(3))) void*)(l), 16, 0, 0)

__device__ __forceinline__ unsigned short rne_bf16(float f) {
    unsigned u = __float_as_uint(f);
    return (unsigned short)((u + 0x7FFFu + ((u >> 16) & 1u)) >> 16);
}
__device__ __forceinline__ float bf16_to_f(unsigned short h) {
    return __uint_as_float((unsigned)h << 16);
}

// ---------------------------------------------------------------------------
// codebook row norms ||c_k||^2  (summation order feeds argmin -- unchanged)
// ---------------------------------------------------------------------------
__global__ __launch_bounds__(256)
void vq_cnorm_kernel(const float* __restrict__ cb, float* __restrict__ cnorm)
{
    const int k = blockIdx.x * 256 + threadIdx.x;  // grid=4
    const float4* row = reinterpret_cast<const float4*>(cb + (size_t)k * 256);
    float s0 = 0.f, s1 = 0.f, s2 = 0.f, s3 = 0.f;
#pragma unroll 8
    for (int i = 0; i < 64; ++i) {
        float4 v = row[i];
        s0 = fmaf(v.x, v.x, s0);
        s1 = fmaf(v.y, v.y, s1);
        s2 = fmaf(v.z, v.z, s2);
        s3 = fmaf(v.w, v.w, s3);
    }
    cnorm[k] = (s0 + s1) + (s2 + s3);
}

// ---------------------------------------------------------------------------
// codebook split + packed/loss init (memset fusion): grid 256
// ---------------------------------------------------------------------------
__global__ __launch_bounds__(256)
void vq_csplit_kernel(const float* __restrict__ cb, unsigned short* __restrict__ c0,
                      unsigned short* __restrict__ c1, unsigned short* __restrict__ c2,
                      unsigned long long* __restrict__ packed, float* __restrict__ loss)
{
    const int b = blockIdx.x, t = threadIdx.x;
    const int idx = b * 256 + t;
    if (t < 128) packed[b * 128 + t] = 0xFFFFFFFFFFFFFFFFull;
    if (b == 0 && t == 255) *loss = 0.f;

    float4 v = reinterpret_cast<const float4*>(cb)[idx];
    float f[4] = { v.x, v.y, v.z, v.w };
    ushort4 h0, h1, h2;
    unsigned short* p0[4] = { &h0.x, &h0.y, &h0.z, &h0.w };
    unsigned short* p1[4] = { &h1.x, &h1.y, &h1.z, &h1.w };
    unsigned short* p2[4] = { &h2.x, &h2.y, &h2.z, &h2.w };
#pragma unroll
    for (int j = 0; j < 4; ++j) {
        unsigned short b0 = rne_bf16(f[j]); float r1 = f[j] - bf16_to_f(b0);
        unsigned short b1 = rne_bf16(r1);   float r2 = r1 - bf16_to_f(b1);
        unsigned short b2 = rne_bf16(r2);
        *p0[j] = b0; *p1[j] = b1; *p2[j] = b2;
    }
    reinterpret_cast<ushort4*>(c0)[idx] = h0;
    reinterpret_cast<ushort4*>(c1)[idx] = h1;
    reinterpret_cast<ushort4*>(c2)[idx] = h2;
}

// ---------------------------------------------------------------------------
// z split+transpose: z[b][d][hw] fp32 -> z0,z1,z2 bf16 [n][d]
// ---------------------------------------------------------------------------
__global__ __launch_bounds__(256)
void vq_zsplit_kernel(const float* __restrict__ z, unsigned short* __restrict__ z0,
                      unsigned short* __restrict__ z1, unsigned short* __restrict__ z2)
{
    __shared__ float zl[64 * 264];
    const int t = threadIdx.x, blk = blockIdx.x;        // 512 blocks
    const int b = blk >> 4, hw0 = (blk & 15) << 6;
    const float* zb = z + ((size_t)b << 18) + hw0;
#pragma unroll 8
    for (int i = 0; i < 64; ++i) {
        int idx = i * 256 + t;
        int d = idx >> 6, hwl = idx & 63;
        zl[hwl * 264 + d] = zb[(size_t)d * 1024 + hwl];
    }
    __syncthreads();
    const int n0 = (b << 10) + hw0;
#pragma unroll
    for (int p = 0; p < 8; ++p) {
        const int hwl = p * 8 + (t >> 5);
        const int d0 = (t & 31) * 8;
        const float* src = &zl[hwl * 264 + d0];
        unsigned short h0[8], h1[8], h2[8];
#pragma unroll
        for (int j = 0; j < 8; ++j) {
            float f = src[j];
            unsigned short b0 = rne_bf16(f);  float r1 = f - bf16_to_f(b0);
            unsigned short b1 = rne_bf16(r1); float r2 = r1 - bf16_to_f(b1);
            unsigned short b2 = rne_bf16(r2);
            h0[j] = b0; h1[j] = b1; h2[j] = b2;
        }
        const size_t o = (size_t)(n0 + hwl) * 256 + d0;
        ushort4 a;
        a = ushort4{h0[0],h0[1],h0[2],h0[3]}; *reinterpret_cast<ushort4*>(z0 + o)     = a;
        a = ushort4{h0[4],h0[5],h0[6],h0[7]}; *reinterpret_cast<ushort4*>(z0 + o + 4) = a;
        a = ushort4{h1[0],h1[1],h1[2],h1[3]}; *reinterpret_cast<ushort4*>(z1 + o)     = a;
        a = ushort4{h1[4],h1[5],h1[6],h1[7]}; *reinterpret_cast<ushort4*>(z1 + o + 4) = a;
        a = ushort4{h2[0],h2[1],h2[2],h2[3]}; *reinterpret_cast<ushort4*>(z2 + o)     = a;
        a = ushort4{h2[4],h2[5],h2[6],h2[7]}; *reinterpret_cast<ushort4*>(z2 + o + 4) = a;
    }
}

// ---------------------------------------------------------------------------
// MFMA GEMM + fused argmin — 256(M)x128(N) tile, 8 waves (4wr x 2wc),
// per-wave 64x64 (acc[4][4] = 64 AGPR), ONE fat phase per K-tile,
// 3-buffer LDS, counted vmcnt(6), 1 barrier/tile.
//
// LDS per buffer: A[2kk][256x32] (32KB) + B[2kk][128x32] (16KB) = 48KB;
// 3 buffers = 144KB -> 1 block/CU, 2 waves/SIMD (unified reg cap 256;
// usage ~170). Grid 1024 = 128 bm x 8 bn, XCD swizzle bijective
// (1024%8==0), bn-fast -> 8 consecutive blocks share the A-panel in L2.
//
// Phase t (buffer cur=t%3): ds_read kk0 frags (4A+4B) -> stage tile t+2
// (6 gl2lds) into buf (t+2)%3 -> 16 MFMA kk0 -> ds_read kk1 frags (regs
// reused) -> 16 MFMA kk1 -> vmcnt(6) [t+1 landed, t+2 flying] -> s_barrier.
// Ledger: prologue stages t0,t1 (12 loads), vmcnt(6) => t0 in. Each phase
// issues 6, waits 6 => FIFO gives t+1 complete. Tail: phase22 vmcnt(0).
// Hazard: stage t+2 writes buf[(t+2)%3] = buf[(t-1)%3], last read in phase
// t-1, separated by that phase's end barrier.
//
// Swizzle (r9-proven, 0 conflicts): planes are [rows][32] bf16, 64B rows;
// bank = (row&1)*16 + slot*4; store chunk c of row r at slot c ^ ((r>>1)&3);
// gl2lds writes linearly -> GLOBAL source chunk pre-swizzled (selem);
// ds_read applies the same XOR (fco). Per-element K-order (kk0,kk1; tiles
// ascending) identical to r9 -> bit-identical distances.
// ---------------------------------------------------------------------------
__global__ __launch_bounds__(512, 1)
void vq_mfma_argmin_kernel(const unsigned short* __restrict__ zp,
                           const unsigned short* __restrict__ cp,
                           const float* __restrict__ cnorm,
                           unsigned long long* __restrict__ packed)
{
    // buffer stride 24576 shorts = 48KB; A kk plane at +kk*8192,
    // B kk plane at +16384+kk*4096
    __shared__ unsigned short Ld[3 * 24576];   // 144KB

    const int tid = threadIdx.x, l = tid & 63, w = tid >> 6;
    const int wr = w >> 1, wc = w & 1;                 // 4 x 2 wave grid
    const int nid = ((blockIdx.x & 7) << 7) | (blockIdx.x >> 3);  // XCD swizzle
    const int bm = nid >> 3, bn = nid & 7;             // 128 x 8 tiles
    const int arow = bm * 256, brow = bn * 128;

    f32x4 acc[4][4];
#pragma unroll
    for (int m = 0; m < 4; ++m)
#pragma unroll
        for (int n = 0; n < 4; ++n) acc[m][n] = f32x4{0.f, 0.f, 0.f, 0.f};

    // staging lane geometry (per issue = 16 rows): lane l -> row l>>2,
    // slot l&3; source chunk pre-swizzled by row bits 1-2 ((l>>3)&3)
    const int srow  = l >> 2;
    const int selem = (((l & 3) ^ ((l >> 3) & 3))) << 3;

    // fragment-read: chunk hi4 of row r at slot hi4 ^ ((r>>1)&3); r ≡ lo16 (16)
    const int lo16 = l & 15, hi4 = l >> 4;
    const int fco = ((hi4 ^ ((lo16 >> 1) & 3))) << 3;

    // stage tile tt (A: 4 issues over 2 kk planes; B: 2 issues) into BUFP
    // segment tables as nibbles: A {0,1,2,0,1,0}, B {0,0,0,1,1,2}
#define STAGE6(tt, BUFP) do {                                                 \
    const int seg_ = (tt) >> 2;                                               \
    const unsigned short* As_ = zp + (size_t)((0x010210 >> (seg_ << 2)) & 3) * 8388608u; \
    const unsigned short* Bs_ = cp + (size_t)((0x211000 >> (seg_ << 2)) & 3) * 262144u;  \
    const int KO_ = (((tt) & 3) << 6) + selem;                                \
    GL2LDS(As_ + (size_t)(arow + w * 32 +  0 + srow) * 256 + KO_,      (BUFP) + (w * 32     ) * 32); \
    GL2LDS(As_ + (size_t)(arow + w * 32 + 16 + srow) * 256 + KO_,      (BUFP) + (w * 32 + 16) * 32); \
    GL2LDS(As_ + (size_t)(arow + w * 32 +  0 + srow) * 256 + KO_ + 32, (BUFP) + 8192 + (w * 32     ) * 32); \
    GL2LDS(As_ + (size_t)(arow + w * 32 + 16 + srow) * 256 + KO_ + 32, (BUFP) + 8192 + (w * 32 + 16) * 32); \
    GL2LDS(Bs_ + (size_t)(brow + w * 16 + srow) * 256 + KO_,           (BUFP) + 16384 + (w * 16) * 32); \
    GL2LDS(Bs_ + (size_t)(brow + w * 16 + srow) * 256 + KO_ + 32,      (BUFP) + 16384 + 4096 + (w * 16) * 32); \
} while (0)

#define VM6  asm volatile("s_waitcnt vmcnt(6)"  ::: "memory")
#define VM0  asm volatile("s_waitcnt vmcnt(0)"  ::: "memory")
#define NOPS ((void)0)
#define FNCE do { asm volatile("" ::: "memory");                              \
                  __builtin_amdgcn_sched_barrier(0); } while (0)
#define SBAR do { asm volatile("" ::: "memory");                              \
                  __builtin_amdgcn_s_barrier();                               \
                  __builtin_amdgcn_sched_barrier(0); } while (0)

#define MFMA16(A0, A1, A2, A3, B0, B1, B2, B3)                                \
    acc[0][0] = __builtin_amdgcn_mfma_f32_16x16x32_bf16(A0, B0, acc[0][0], 0,0,0); \
    acc[0][1] = __builtin_amdgcn_mfma_f32_16x16x32_bf16(A0, B1, acc[0][1], 0,0,0); \
    acc[0][2] = __builtin_amdgcn_mfma_f32_16x16x32_bf16(A0, B2, acc[0][2], 0,0,0); \
    acc[0][3] = __builtin_amdgcn_mfma_f32_16x16x32_bf16(A0, B3, acc[0][3], 0,0,0); \
    acc[1][0] = __builtin_amdgcn_mfma_f32_16x16x32_bf16(A1, B0, acc[1][0], 0,0,0); \
    acc[1][1] = __builtin_amdgcn_mfma_f32_16x16x32_bf16(A1, B1, acc[1][1], 0,0,0); \
    acc[1][2] = __builtin_amdgcn_mfma_f32_16x16x32_bf16(A1, B2, acc[1][2], 0,0,0); \
    acc[1][3] = __builtin_amdgcn_mfma_f32_16x16x32_bf16(A1, B3, acc[1][3], 0,0,0); \
    acc[2][0] = __builtin_amdgcn_mfma_f32_16x16x32_bf16(A2, B0, acc[2][0], 0,0,0); \
    acc[2][1] = __builtin_amdgcn_mfma_f32_16x16x32_bf16(A2, B1, acc[2][1], 0,0,0); \
    acc[2][2] = __builtin_amdgcn_mfma_f32_16x16x32_bf16(A2, B2, acc[2][2], 0,0,0); \
    acc[2][3] = __builtin_amdgcn_mfma_f32_16x16x32_bf16(A2, B3, acc[2][3], 0,0,0); \
    acc[3][0] = __builtin_amdgcn_mfma_f32_16x16x32_bf16(A3, B0, acc[3][0], 0,0,0); \
    acc[3][1] = __builtin_amdgcn_mfma_f32_16x16x32_bf16(A3, B1, acc[3][1], 0,0,0); \
    acc[3][2] = __builtin_amdgcn_mfma_f32_16x16x32_bf16(A3, B2, acc[3][2], 0,0,0); \
    acc[3][3] = __builtin_amdgcn_mfma_f32_16x16x32_bf16(A3, B3, acc[3][3], 0,0,0)

    // fat phase: kk0 {reads, stage, MFMA16} then kk1 {reads, MFMA16}, then wait+barrier
#define PH_T(BUFP, STAGESTMT, VMSTMT, BARSTMT) do {                           \
    const unsigned short* Ap_ = (BUFP);                                       \
    const unsigned short* Bp_ = (BUFP) + 16384;                               \
    bf16x8 a0, a1, a2, a3, b0, b1, b2, b3;                                    \
    a0 = *(const bf16x8*)&Ap_[(wr*64 + 0*16 + lo16)*32 + fco];                \
    a1 = *(const bf16x8*)&Ap_[(wr*64 + 1*16 + lo16)*32 + fco];                \
    a2 = *(const bf16x8*)&Ap_[(wr*64 + 2*16 + lo16)*32 + fco];                \
    a3 = *(const bf16x8*)&Ap_[(wr*64 + 3*16 + lo16)*32 + fco];                \
    b0 = *(const bf16x8*)&Bp_[(wc*64 + 0*16 + lo16)*32 + fco];                \
    b1 = *(const bf16x8*)&Bp_[(wc*64 + 1*16 + lo16)*32 + fco];                \
    b2 = *(const bf16x8*)&Bp_[(wc*64 + 2*16 + lo16)*32 + fco];                \
    b3 = *(const bf16x8*)&Bp_[(wc*64 + 3*16 + lo16)*32 + fco];                \
    STAGESTMT;                                                                \
    FNCE;                                                                     \
    __builtin_amdgcn_s_setprio(1);                                            \
    MFMA16(a0, a1, a2, a3, b0, b1, b2, b3);                                   \
    __builtin_amdgcn_s_setprio(0);                                            \
    a0 = *(const bf16x8*)&Ap_[8192 + (wr*64 + 0*16 + lo16)*32 + fco];         \
    a1 = *(const bf16x8*)&Ap_[8192 + (wr*64 + 1*16 + lo16)*32 + fco];         \
    a2 = *(const bf16x8*)&Ap_[8192 + (wr*64 + 2*16 + lo16)*32 + fco];         \
    a3 = *(const bf16x8*)&Ap_[8192 + (wr*64 + 3*16 + lo16)*32 + fco];         \
    b0 = *(const bf16x8*)&Bp_[4096 + (wc*64 + 0*16 + lo16)*32 + fco];         \
    b1 = *(const bf16x8*)&Bp_[4096 + (wc*64 + 1*16 + lo16)*32 + fco];         \
    b2 = *(const bf16x8*)&Bp_[4096 + (wc*64 + 2*16 + lo16)*32 + fco];         \
    b3 = *(const bf16x8*)&Bp_[4096 + (wc*64 + 3*16 + lo16)*32 + fco];         \
    FNCE;                                                                     \
    __builtin_amdgcn_s_setprio(1);                                            \
    MFMA16(a0, a1, a2, a3, b0, b1, b2, b3);                                   \
    __builtin_amdgcn_s_setprio(0);                                            \
    VMSTMT;                                                                   \
    BARSTMT;                                                                  \
} while (0)

    // prologue: stage tiles 0,1; wait tile 0 (leave tile 1's 6 flying)
    STAGE6(0, Ld);
    STAGE6(1, Ld + 24576);
    VM6;
    SBAR;

    // t = 0..20 in groups of 3 (cur = t%3, stage target = (t+2)%3)
    for (int t = 0; t < 21; t += 3) {
        PH_T(Ld,             STAGE6(t + 2, Ld + 2 * 24576), VM6, SBAR);
        PH_T(Ld + 24576,     STAGE6(t + 3, Ld),             VM6, SBAR);
        PH_T(Ld + 2 * 24576, STAGE6(t + 4, Ld + 24576),     VM6, SBAR);
    }
    // t=21 (cur=0, stages tile 23 into buf2), t=22 (cur=1, drain), t=23 (cur=2)
    PH_T(Ld,             STAGE6(23, Ld + 2 * 24576), VM6, SBAR);
    PH_T(Ld + 24576,     NOPS,                       VM0, SBAR);
    PH_T(Ld + 2 * 24576, NOPS,                       NOPS, NOPS);

#undef PH_T
#undef MFMA16
#undef STAGE6

    // epilogue: fused argmin. col = brow + wc*64 + n*16 + lo16
    int coln[4]; float cnv[4];
#pragma unroll
    for (int n = 0; n < 4; ++n) {
        coln[n] = brow + wc * 64 + n * 16 + lo16;
        cnv[n] = cnorm[coln[n]];
    }
#pragma unroll
    for (int m = 0; m < 4; ++m) {
#pragma unroll
        for (int j = 0; j < 4; ++j) {
            unsigned long long best = 0xFFFFFFFFFFFFFFFFull;
#pragma unroll
            for (int n = 0; n < 4; ++n) {
                float d = fmaf(-2.0f, acc[m][n][j], cnv[n]);
                unsigned u = __float_as_uint(d);
                u = (u & 0x80000000u) ? ~u : (u | 0x80000000u);   // order-preserving map
                unsigned long long pk = ((unsigned long long)u << 32) | (unsigned)coln[n];
                best = pk < best ? pk : best;
            }
#pragma unroll
            for (int mask = 1; mask <= 8; mask <<= 1) {
                unsigned long long o = __shfl_xor(best, mask, 64);
                best = o < best ? o : best;
            }
            if (lo16 == 0) {
                const int row = arow + wr * 64 + m * 16 + hi4 * 4 + j;
                atomicMin(&packed[row], best);
            }
        }
    }
}

// ---------------------------------------------------------------------------
// gather (packed): z_q write, out_idx write, vq_loss accumulate
// ---------------------------------------------------------------------------
__global__ __launch_bounds__(256, 2)
void vq_gather_packed_kernel(const float* __restrict__ cb, const float* __restrict__ z,
                             const unsigned long long* __restrict__ packed,
                             float* __restrict__ out_zq, float* __restrict__ out_idx,
                             float* __restrict__ loss)
{
    __shared__ float rows[64 * 257];
    __shared__ int   ks[64];
    __shared__ float wsum[4];

    const int t   = threadIdx.x;
    const int blk = blockIdx.x;            // 512 blocks
    const int b   = blk >> 4;
    const int hw0 = (blk & 15) << 6;
    const int n0  = blk << 6;

    if (t < 64) {
        const int k = (int)(packed[n0 + t] & 0xFFFFFFFFull);
        ks[t] = k;
        out_idx[n0 + t] = (float)k;
    }
    __syncthreads();

#pragma unroll 4
    for (int i = 0; i < 64; ++i) {
        rows[i * 257 + t] = cb[(size_t)ks[i] * 256 + t];
    }
    __syncthreads();

    const int dq = t >> 6;
    const int hw = t & 63;
    const size_t obase = ((size_t)b << 18) + hw0 + hw;
    float sum = 0.f;
#pragma unroll 4
    for (int dd = 0; dd < 64; ++dd) {
        const int d = (dq << 6) + dd;
        const float  q  = rows[hw * 257 + d];
        const size_t a  = obase + (size_t)d * 1024;
        const float  zv = z[a];
        out_zq[a] = q;
        const float diff = q - zv;
        sum = fmaf(diff, diff, sum);
    }
#pragma unroll
    for (int m = 1; m <= 32; m <<= 1) sum += __shfl_xor(sum, m, 64);
    if ((t & 63) == 0) wsum[t >> 6] = sum;
    __syncthreads();
    if (t == 0) {
        const float s = (wsum[0] + wsum[1]) + (wsum[2] + wsum[3]);
        atomicAdd(loss, s * (1.25f / 8388608.0f));   // (1+0.25)*SSE/(B*D*H*W)
    }
}

// ===========================================================================
// FALLBACK PATH (ws too small): round-3 fp32 VALU kernels, known-passing.
// ===========================================================================
__global__ __launch_bounds__(256)
void vq_transpose_kernel(const float* __restrict__ cb, float* __restrict__ ctT)
{
    __shared__ float tile[64 * 65];
    const int t  = threadIdx.x;
    const int kb = blockIdx.x >> 2, db = blockIdx.x & 3;
    const int k0 = kb << 6, d0 = db << 6;
#pragma unroll
    for (int i = 0; i < 16; ++i) {
        int idx = i * 256 + t;
        int r = idx >> 6, c = idx & 63;
        tile[r * 65 + c] = cb[(size_t)(k0 + r) * 256 + d0 + c];
    }
    __syncthreads();
#pragma unroll
    for (int i = 0; i < 16; ++i) {
        int idx = i * 256 + t;
        int r = idx >> 6, c = idx & 63;
        ctT[(size_t)(d0 + r) * 1024 + k0 + c] = tile[c * 65 + r];
    }
}

__global__ __launch_bounds__(256)
void vq_cnorm_fb_kernel(const float* __restrict__ cb, float* __restrict__ cnorm)
{
    const int k = blockIdx.x * 256 + threadIdx.x;  // grid=4
    const float4* row = reinterpret_cast<const float4*>(cb + (size_t)k * 256);
    float s0 = 0.f, s1 = 0.f, s2 = 0.f, s3 = 0.f;
#pragma unroll 8
    for (int i = 0; i < 64; ++i) {
        float4 v = row[i];
        s0 = fmaf(v.x, v.x, s0);
        s1 = fmaf(v.y, v.y, s1);
        s2 = fmaf(v.z, v.z, s2);
        s3 = fmaf(v.w, v.w, s3);
    }
    cnorm[k] = (s0 + s1) + (s2 + s3);
}

__global__ __launch_bounds__(512, 2)
void vq_argmin_kernel(const float* __restrict__ z, const float* __restrict__ ctT,
                      const float* __restrict__ cnorm, int* __restrict__ codes,
                      float* __restrict__ out_idx)
{
    __shared__ float zt[256 * 64];
    __shared__ float ct[16 * 256];
    const int t = threadIdx.x, tx = t & 63, ty = t >> 6, p0 = ty << 3;
    const int blk = blockIdx.x, b = blk >> 4, hw0 = (blk & 15) << 6;
    const float* zbase = z + ((size_t)b << 18) + hw0;
#pragma unroll
    for (int i = 0; i < 8; ++i) {
        int idx = i * 512 + t;
        int d = idx >> 4, c4 = (idx & 15) << 2;
        float4 v = *reinterpret_cast<const float4*>(zbase + (size_t)d * 1024 + c4);
        *reinterpret_cast<float4*>(&zt[d * 64 + c4]) = v;
    }
    float minv[8]; int mini[8];
#pragma unroll
    for (int i = 0; i < 8; ++i) { minv[i] = 3.0e38f; mini[i] = 0; }
    const float* zrd = &zt[p0];
    const float* crd = &ct[tx << 2];
    for (int kt = 0; kt < 4; ++kt) {
        const int k0 = kt << 8;
        float acc[8][4];
#pragma unroll
        for (int i = 0; i < 8; ++i)
#pragma unroll
            for (int j = 0; j < 4; ++j) acc[i][j] = 0.f;
        for (int dc = 0; dc < 16; ++dc) {
            const int d0 = dc << 4;
            __syncthreads();
#pragma unroll
            for (int i = 0; i < 2; ++i) {
                int idx = i * 512 + t;
                int r = idx >> 6, c4 = (idx & 63) << 2;
                float4 v = *reinterpret_cast<const float4*>(ctT + (size_t)(d0 + r) * 1024 + k0 + c4);
                *reinterpret_cast<float4*>(&ct[r * 256 + c4]) = v;
            }
            __syncthreads();
            const float* zp = zrd + d0 * 64;
#pragma unroll
            for (int d = 0; d < 16; ++d) {
                float4 za = *reinterpret_cast<const float4*>(zp + d * 64);
                float4 zb = *reinterpret_cast<const float4*>(zp + d * 64 + 4);
                float4 cc = *reinterpret_cast<const float4*>(crd + d * 256);
#define VQ_FMA_ROW(ii, zv)                          \
                acc[ii][0] = fmaf(zv, cc.x, acc[ii][0]); \
                acc[ii][1] = fmaf(zv, cc.y, acc[ii][1]); \
                acc[ii][2] = fmaf(zv, cc.z, acc[ii][2]); \
                acc[ii][3] = fmaf(zv, cc.w, acc[ii][3]);
                VQ_FMA_ROW(0, za.x) VQ_FMA_ROW(1, za.y) VQ_FMA_ROW(2, za.z) VQ_FMA_ROW(3, za.w)
                VQ_FMA_ROW(4, zb.x) VQ_FMA_ROW(5, zb.y) VQ_FMA_ROW(6, zb.z) VQ_FMA_ROW(7, zb.w)
#undef VQ_FMA_ROW
            }
        }
#pragma unroll
        for (int j = 0; j < 4; ++j) {
            const int k = k0 + (tx << 2) + j;
            const float cn = cnorm[k];
#pragma unroll
            for (int i = 0; i < 8; ++i) {
                float dist = fmaf(-2.0f, acc[i][j], cn);
                if (dist < minv[i]) { minv[i] = dist; mini[i] = k; }
            }
        }
    }
#pragma unroll
    for (int m = 1; m <= 32; m <<= 1) {
#pragma unroll
        for (int i = 0; i < 8; ++i) {
            float ov = __shfl_xor(minv[i], m, 64);
            int   oi = __shfl_xor(mini[i], m, 64);
            if (ov < minv[i] || (ov == minv[i] && oi < mini[i])) { minv[i] = ov; mini[i] = oi; }
        }
    }
    if (tx == 0) {
        const int n0 = (blk << 6) + p0;
#pragma unroll
        for (int i = 0; i < 8; ++i) {
            codes[n0 + i]   = mini[i];
            out_idx[n0 + i] = (float)mini[i];
        }
    }
}

__global__ __launch_bounds__(256, 2)
void vq_gather_kernel(const float* __restrict__ cb, const float* __restrict__ z,
                      const int* __restrict__ codes, float* __restrict__ out_zq,
                      float* __restrict__ loss)
{
    __shared__ float rows[64 * 257];
    __shared__ int   ks[64];
    __shared__ float wsum[4];
    const int t = threadIdx.x, blk = blockIdx.x;
    const int b = blk >> 4, hw0 = (blk & 15) << 6, n0 = blk << 6;
    if (t < 64) ks[t] = codes[n0 + t];
    __syncthreads();
#pragma unroll 4
    for (int i = 0; i < 64; ++i) rows[i * 257 + t] = cb[(size_t)ks[i] * 256 + t];
    __syncthreads();
    const int dq = t >> 6, hw = t & 63;
    const size_t obase = ((size_t)b << 18) + hw0 + hw;
    float sum = 0.f;
#pragma unroll 4
    for (int dd = 0; dd < 64; ++dd) {
        const int d = (dq << 6) + dd;
        const float  q  = rows[hw * 257 + d];
        const size_t a  = obase + (size_t)d * 1024;
        const float  zv = z[a];
        out_zq[a] = q;
        const float diff = q - zv;
        sum = fmaf(diff, diff, sum);
    }
#pragma unroll
    for (int m = 1; m <= 32; m <<= 1) sum += __shfl_xor(sum, m, 64);
    if ((t & 63) == 0) wsum[t >> 6] = sum;
    __syncthreads();
    if (t == 0) {
        const float s = (wsum[0] + wsum[1]) + (wsum[2] + wsum[3]);
        atomicAdd(loss, s * (1.25f / 8388608.0f));
    }
}

// ---------------------------------------------------------------------------
extern "C" void kernel_launch(void* const* d_in, const int* in_sizes, int n_in,
                              void* d_out, int out_size, void* d_ws, size_t ws_size,
                              hipStream_t stream)
{
    (void)in_sizes; (void)n_in; (void)out_size;

    const float* z  = (const float*)d_in[0];   // 32*256*32*32 fp32
    const float* cb = (const float*)d_in[1];   // 1024*256 fp32

    float* out      = (float*)d_out;
    float* out_zq   = out;                     // 8388608
    float* out_idx  = out + 8388608;           // 32768 (indices as float values)
    float* out_loss = out + 8421376;           // 1

    // MFMA-path workspace: packed(256KB) | z0|z1|z2 (16MB each) | c0|c1|c2 | cnorm
    const size_t NEED = 262144ull + 3ull * 16777216ull + 3ull * 524288ull + 4096ull;

    if (ws_size >= NEED) {
        unsigned long long* packed = (unsigned long long*)d_ws;
        unsigned short* z0 = (unsigned short*)((char*)d_ws + 262144);
        unsigned short* z1 = z0 + 8388608u;
        unsigned short* z2 = z1 + 8388608u;
        unsigned short* c0 = z2 + 8388608u;
        unsigned short* c1 = c0 + 262144u;
        unsigned short* c2 = c1 + 262144u;
        float* cnorm = (float*)(c2 + 262144u);

        vq_csplit_kernel<<<256, 256, 0, stream>>>(cb, c0, c1, c2, packed, out_loss);
        vq_cnorm_kernel<<<4, 256, 0, stream>>>(cb, cnorm);
        vq_zsplit_kernel<<<512, 256, 0, stream>>>(z, z0, z1, z2);
        vq_mfma_argmin_kernel<<<1024, 512, 0, stream>>>(z0, c0, cnorm, packed);
        vq_gather_packed_kernel<<<512, 256, 0, stream>>>(cb, z, packed, out_zq, out_idx, out_loss);
    } else {
        // fallback: round-3 fp32 path (ws >= 1.38MB known OK)
        float* ctT   = (float*)d_ws;
        float* cnorm = ctT + 256 * 1024;
        int*   codes = (int*)(cnorm + 1024);

        hipMemsetAsync(out_loss, 0, sizeof(float), stream);
        vq_transpose_kernel<<<64, 256, 0, stream>>>(cb, ctT);
        vq_cnorm_fb_kernel<<<4, 256, 0, stream>>>(cb, cnorm);
        vq_argmin_kernel<<<512, 512, 0, stream>>>(z, ctT, cnorm, codes, out_idx);
        vq_gather_kernel<<<512, 256, 0, stream>>>(cb, z, codes, out_zq, out_loss);
    }
}

// Round 14
// 172.553 us; speedup vs baseline: 1.0436x; 1.0436x over previous
//
#include <hip/hip_runtime.h>
#include <cstdint>
#include <cstddef>

// Problem constants (B=32, D=256, H=32, W=32, K=1024), N = B*H*W = 32768.
// MFMA path: fp32 -> 3x bf16 split; 6 concat-K segments -> bf16 GEMM
// M=32768 N=1024 K=1536; error ~ fp32 accumulation (numpy-grade).
//
// History: r9 (256², 128x64 waves, 8 barriers/tile) 114.9µs = best; r10-r12
// spilled (reg cap 256, acc alone 128); r13 (256x128, 64x64 waves, acc 64,
// 1 barrier/tile) NO spill but 142µs -> falsified "barriers are the cost".
// Resource audit: LDS frag-read traffic = (1/Nw+1/Mw) B/FLOP is co-dominant
// with MFMA; r13's schedule serializes read-batch -> MFMA-cluster. r14 =
// r13 geometry + REGISTER FRAG DOUBLE-BUFFER: each half-tile's ds_reads
// issue in parallel with the other half's 16 independent MFMAs (X/Y named
// sets; no runtime indexing -> no scratch, rule #20). One barrier/tile at
// the mid-phase vmcnt(6)+lgkmcnt(0) point. Floors: MFMA 41µs, LDS 31-46µs;
// overlapped target = max ~ 60-75µs GEMM.
// Accumulation K-order per element unchanged -> bit-identical distances.

typedef __attribute__((ext_vector_type(8))) short bf16x8;
typedef __attribute__((ext_vector_type(4))) float f32x4;

#define GL2LDS(g, l) __builtin_amdgcn_global_load_lds( \
    (__attribute__((address_space(1))) const void*)(g), \
    (__attribute__((address_space(3))) void*)(l), 16, 0, 0)

__device__ __forceinline__ unsigned short rne_bf16(float f) {
    unsigned u = __float_as_uint(f);
    return (unsigned short)((u + 0x7FFFu + ((u >> 16) & 1u)) >> 16);
}
__device__ __forceinline__ float bf16_to_f(unsigned short h) {
    return __uint_as_float((unsigned)h << 16);
}

// ---------------------------------------------------------------------------
// codebook row norms ||c_k||^2  (summation order feeds argmin -- unchanged)
// ---------------------------------------------------------------------------
__global__ __launch_bounds__(256)
void vq_cnorm_kernel(const float* __restrict__ cb, float* __restrict__ cnorm)
{
    const int k = blockIdx.x * 256 + threadIdx.x;  // grid=4
    const float4* row = reinterpret_cast<const float4*>(cb + (size_t)k * 256);
    float s0 = 0.f, s1 = 0.f, s2 = 0.f, s3 = 0.f;
#pragma unroll 8
    for (int i = 0; i < 64; ++i) {
        float4 v = row[i];
        s0 = fmaf(v.x, v.x, s0);
        s1 = fmaf(v.y, v.y, s1);
        s2 = fmaf(v.z, v.z, s2);
        s3 = fmaf(v.w, v.w, s3);
    }
    cnorm[k] = (s0 + s1) + (s2 + s3);
}

// ---------------------------------------------------------------------------
// codebook split + packed/loss init (memset fusion): grid 256
// ---------------------------------------------------------------------------
__global__ __launch_bounds__(256)
void vq_csplit_kernel(const float* __restrict__ cb, unsigned short* __restrict__ c0,
                      unsigned short* __restrict__ c1, unsigned short* __restrict__ c2,
                      unsigned long long* __restrict__ packed, float* __restrict__ loss)
{
    const int b = blockIdx.x, t = threadIdx.x;
    const int idx = b * 256 + t;
    if (t < 128) packed[b * 128 + t] = 0xFFFFFFFFFFFFFFFFull;
    if (b == 0 && t == 255) *loss = 0.f;

    float4 v = reinterpret_cast<const float4*>(cb)[idx];
    float f[4] = { v.x, v.y, v.z, v.w };
    ushort4 h0, h1, h2;
    unsigned short* p0[4] = { &h0.x, &h0.y, &h0.z, &h0.w };
    unsigned short* p1[4] = { &h1.x, &h1.y, &h1.z, &h1.w };
    unsigned short* p2[4] = { &h2.x, &h2.y, &h2.z, &h2.w };
#pragma unroll
    for (int j = 0; j < 4; ++j) {
        unsigned short b0 = rne_bf16(f[j]); float r1 = f[j] - bf16_to_f(b0);
        unsigned short b1 = rne_bf16(r1);   float r2 = r1 - bf16_to_f(b1);
        unsigned short b2 = rne_bf16(r2);
        *p0[j] = b0; *p1[j] = b1; *p2[j] = b2;
    }
    reinterpret_cast<ushort4*>(c0)[idx] = h0;
    reinterpret_cast<ushort4*>(c1)[idx] = h1;
    reinterpret_cast<ushort4*>(c2)[idx] = h2;
}

// ---------------------------------------------------------------------------
// z split+transpose: z[b][d][hw] fp32 -> z0,z1,z2 bf16 [n][d]
// ---------------------------------------------------------------------------
__global__ __launch_bounds__(256)
void vq_zsplit_kernel(const float* __restrict__ z, unsigned short* __restrict__ z0,
                      unsigned short* __restrict__ z1, unsigned short* __restrict__ z2)
{
    __shared__ float zl[64 * 264];
    const int t = threadIdx.x, blk = blockIdx.x;        // 512 blocks
    const int b = blk >> 4, hw0 = (blk & 15) << 6;
    const float* zb = z + ((size_t)b << 18) + hw0;
#pragma unroll 8
    for (int i = 0; i < 64; ++i) {
        int idx = i * 256 + t;
        int d = idx >> 6, hwl = idx & 63;
        zl[hwl * 264 + d] = zb[(size_t)d * 1024 + hwl];
    }
    __syncthreads();
    const int n0 = (b << 10) + hw0;
#pragma unroll
    for (int p = 0; p < 8; ++p) {
        const int hwl = p * 8 + (t >> 5);
        const int d0 = (t & 31) * 8;
        const float* src = &zl[hwl * 264 + d0];
        unsigned short h0[8], h1[8], h2[8];
#pragma unroll
        for (int j = 0; j < 8; ++j) {
            float f = src[j];
            unsigned short b0 = rne_bf16(f);  float r1 = f - bf16_to_f(b0);
            unsigned short b1 = rne_bf16(r1); float r2 = r1 - bf16_to_f(b1);
            unsigned short b2 = rne_bf16(r2);
            h0[j] = b0; h1[j] = b1; h2[j] = b2;
        }
        const size_t o = (size_t)(n0 + hwl) * 256 + d0;
        ushort4 a;
        a = ushort4{h0[0],h0[1],h0[2],h0[3]}; *reinterpret_cast<ushort4*>(z0 + o)     = a;
        a = ushort4{h0[4],h0[5],h0[6],h0[7]}; *reinterpret_cast<ushort4*>(z0 + o + 4) = a;
        a = ushort4{h1[0],h1[1],h1[2],h1[3]}; *reinterpret_cast<ushort4*>(z1 + o)     = a;
        a = ushort4{h1[4],h1[5],h1[6],h1[7]}; *reinterpret_cast<ushort4*>(z1 + o + 4) = a;
        a = ushort4{h2[0],h2[1],h2[2],h2[3]}; *reinterpret_cast<ushort4*>(z2 + o)     = a;
        a = ushort4{h2[4],h2[5],h2[6],h2[7]}; *reinterpret_cast<ushort4*>(z2 + o + 4) = a;
    }
}

// ---------------------------------------------------------------------------
// MFMA GEMM + fused argmin — 256(M)x128(N) tile, 8 waves (4wr x 2wc),
// per-wave 64x64 (acc[4][4] = 64 AGPR), register frag DOUBLE-BUFFER,
// 3-buffer LDS, counted vmcnt(6), 1 barrier/tile (mid-phase).
//
// LDS per buffer: A[2kk][256x32] (32KB) + B[2kk][128x32] (16KB) = 48KB;
// 3 buffers = 144KB -> 1 block/CU. Regs: acc 64 + 16 frags (64) + addr
// ~60 = ~190 of 256 @ 2 waves/SIMD -- headroom, no spill (r10-12 lesson).
//
// Phase t (cur buf C=t%3, next buf N=(t+1)%3):
//   first half : MFMA kk0(t) [X frags, pre-read] ∥ ds_read kk1(t)->Y
//                ∥ issue STAGE6(t+2) -> buf (t+2)%3
//   mid        : lgkmcnt(0); vmcnt(6); s_barrier  (tile t+1 in for ALL waves)
//   second half: MFMA kk1(t) [Y] ∥ ds_read kk0(t+1)->X   [from buf N]
// Ledger: prologue stages t0,t1 (12), vmcnt(6) -> t0 in; each phase issues
// 6, mid-waits 6 -> FIFO gives t+1 in. Tail: phase22 vmcnt(0), phase23 none.
// WAR: STAGE6(t+2) writes buf[(t-1)%3]; its last reads (kk1(t-1)) were
// lgkm-drained before the t-1 mid-barrier that every wave passed. Reads of
// buf never cross an SBAR (memory-clobber + sched_barrier in SBAR).
//
// Swizzle (r9/r13-proven, 0 conflicts): planes [rows][32] bf16, 64B rows;
// store chunk c of row r at slot c ^ ((r>>1)&3); gl2lds writes linearly ->
// GLOBAL source chunk pre-swizzled (selem); ds_read applies same XOR (fco).
// Per-element K-order (kk0,kk1; tiles ascending) identical -> bit-identical.
// ---------------------------------------------------------------------------
__global__ __launch_bounds__(512, 1)
void vq_mfma_argmin_kernel(const unsigned short* __restrict__ zp,
                           const unsigned short* __restrict__ cp,
                           const float* __restrict__ cnorm,
                           unsigned long long* __restrict__ packed)
{
    // buffer stride 24576 shorts = 48KB; A kk plane at +kk*8192,
    // B kk plane at +16384+kk*4096
    __shared__ unsigned short Ld[3 * 24576];   // 144KB

    const int tid = threadIdx.x, l = tid & 63, w = tid >> 6;
    const int wr = w >> 1, wc = w & 1;                 // 4 x 2 wave grid
    const int nid = ((blockIdx.x & 7) << 7) | (blockIdx.x >> 3);  // XCD swizzle
    const int bm = nid >> 3, bn = nid & 7;             // 128 x 8 tiles
    const int arow = bm * 256, brow = bn * 128;

    f32x4 acc[4][4];
#pragma unroll
    for (int m = 0; m < 4; ++m)
#pragma unroll
        for (int n = 0; n < 4; ++n) acc[m][n] = f32x4{0.f, 0.f, 0.f, 0.f};

    // staging lane geometry (per issue = 16 rows): lane l -> row l>>2,
    // slot l&3; source chunk pre-swizzled by row bits 1-2 ((l>>3)&3)
    const int srow  = l >> 2;
    const int selem = (((l & 3) ^ ((l >> 3) & 3))) << 3;

    // fragment-read: chunk hi4 of row r at slot hi4 ^ ((r>>1)&3); r ≡ lo16 (16)
    const int lo16 = l & 15, hi4 = l >> 4;
    const int fco = ((hi4 ^ ((lo16 >> 1) & 3))) << 3;

    // stage tile tt (A: 4 issues over 2 kk planes; B: 2 issues) into BUFP
    // segment tables as nibbles: A {0,1,2,0,1,0}, B {0,0,0,1,1,2}
#define STAGE6(tt, BUFP) do {                                                 \
    const int seg_ = (tt) >> 2;                                               \
    const unsigned short* As_ = zp + (size_t)((0x010210 >> (seg_ << 2)) & 3) * 8388608u; \
    const unsigned short* Bs_ = cp + (size_t)((0x211000 >> (seg_ << 2)) & 3) * 262144u;  \
    const int KO_ = (((tt) & 3) << 6) + selem;                                \
    GL2LDS(As_ + (size_t)(arow + w * 32 +  0 + srow) * 256 + KO_,      (BUFP) + (w * 32     ) * 32); \
    GL2LDS(As_ + (size_t)(arow + w * 32 + 16 + srow) * 256 + KO_,      (BUFP) + (w * 32 + 16) * 32); \
    GL2LDS(As_ + (size_t)(arow + w * 32 +  0 + srow) * 256 + KO_ + 32, (BUFP) + 8192 + (w * 32     ) * 32); \
    GL2LDS(As_ + (size_t)(arow + w * 32 + 16 + srow) * 256 + KO_ + 32, (BUFP) + 8192 + (w * 32 + 16) * 32); \
    GL2LDS(Bs_ + (size_t)(brow + w * 16 + srow) * 256 + KO_,           (BUFP) + 16384 + (w * 16) * 32); \
    GL2LDS(Bs_ + (size_t)(brow + w * 16 + srow) * 256 + KO_ + 32,      (BUFP) + 16384 + 4096 + (w * 16) * 32); \
} while (0)

#define VM6  asm volatile("s_waitcnt vmcnt(6)"  ::: "memory")
#define VM0  asm volatile("s_waitcnt vmcnt(0)"  ::: "memory")
#define LK0  asm volatile("s_waitcnt lgkmcnt(0)" ::: "memory")
#define NOPS ((void)0)
#define SBAR do { asm volatile("" ::: "memory");                              \
                  __builtin_amdgcn_s_barrier();                               \
                  __builtin_amdgcn_sched_barrier(0); } while (0)

    // named frag sets (static indexing -- rule #20)
    bf16x8 xa0, xa1, xa2, xa3, xb0, xb1, xb2, xb3;   // kk0 set
    bf16x8 ya0, ya1, ya2, ya3, yb0, yb1, yb2, yb3;   // kk1 set

#define READ_A(d0, d1, d2, d3, PLANE)                                         \
    d0 = *(const bf16x8*)&(PLANE)[(wr*64 + 0*16 + lo16)*32 + fco];            \
    d1 = *(const bf16x8*)&(PLANE)[(wr*64 + 1*16 + lo16)*32 + fco];            \
    d2 = *(const bf16x8*)&(PLANE)[(wr*64 + 2*16 + lo16)*32 + fco];            \
    d3 = *(const bf16x8*)&(PLANE)[(wr*64 + 3*16 + lo16)*32 + fco]
#define READ_B(d0, d1, d2, d3, PLANE)                                         \
    d0 = *(const bf16x8*)&(PLANE)[(wc*64 + 0*16 + lo16)*32 + fco];            \
    d1 = *(const bf16x8*)&(PLANE)[(wc*64 + 1*16 + lo16)*32 + fco];            \
    d2 = *(const bf16x8*)&(PLANE)[(wc*64 + 2*16 + lo16)*32 + fco];            \
    d3 = *(const bf16x8*)&(PLANE)[(wc*64 + 3*16 + lo16)*32 + fco]

#define MFMA16(A0, A1, A2, A3, B0, B1, B2, B3)                                \
    acc[0][0] = __builtin_amdgcn_mfma_f32_16x16x32_bf16(A0, B0, acc[0][0], 0,0,0); \
    acc[0][1] = __builtin_amdgcn_mfma_f32_16x16x32_bf16(A0, B1, acc[0][1], 0,0,0); \
    acc[0][2] = __builtin_amdgcn_mfma_f32_16x16x32_bf16(A0, B2, acc[0][2], 0,0,0); \
    acc[0][3] = __builtin_amdgcn_mfma_f32_16x16x32_bf16(A0, B3, acc[0][3], 0,0,0); \
    acc[1][0] = __builtin_amdgcn_mfma_f32_16x16x32_bf16(A1, B0, acc[1][0], 0,0,0); \
    acc[1][1] = __builtin_amdgcn_mfma_f32_16x16x32_bf16(A1, B1, acc[1][1], 0,0,0); \
    acc[1][2] = __builtin_amdgcn_mfma_f32_16x16x32_bf16(A1, B2, acc[1][2], 0,0,0); \
    acc[1][3] = __builtin_amdgcn_mfma_f32_16x16x32_bf16(A1, B3, acc[1][3], 0,0,0); \
    acc[2][0] = __builtin_amdgcn_mfma_f32_16x16x32_bf16(A2, B0, acc[2][0], 0,0,0); \
    acc[2][1] = __builtin_amdgcn_mfma_f32_16x16x32_bf16(A2, B1, acc[2][1], 0,0,0); \
    acc[2][2] = __builtin_amdgcn_mfma_f32_16x16x32_bf16(A2, B2, acc[2][2], 0,0,0); \
    acc[2][3] = __builtin_amdgcn_mfma_f32_16x16x32_bf16(A2, B3, acc[2][3], 0,0,0); \
    acc[3][0] = __builtin_amdgcn_mfma_f32_16x16x32_bf16(A3, B0, acc[3][0], 0,0,0); \
    acc[3][1] = __builtin_amdgcn_mfma_f32_16x16x32_bf16(A3, B1, acc[3][1], 0,0,0); \
    acc[3][2] = __builtin_amdgcn_mfma_f32_16x16x32_bf16(A3, B2, acc[3][2], 0,0,0); \
    acc[3][3] = __builtin_amdgcn_mfma_f32_16x16x32_bf16(A3, B3, acc[3][3], 0,0,0)

    // phase: BUFC = buf of tile t, BUFN = buf of tile t+1
#define PH(BUFC, BUFN, STAGESTMT, VMSTMT, BARSTMT, RDNEXT) do {               \
    /* first half: read kk1 -> Y, stage, MFMA kk0 with X (independent) */     \
    READ_A(ya0, ya1, ya2, ya3, (BUFC) + 8192);                                \
    READ_B(yb0, yb1, yb2, yb3, (BUFC) + 16384 + 4096);                        \
    STAGESTMT;                                                                \
    __builtin_amdgcn_s_setprio(1);                                            \
    MFMA16(xa0, xa1, xa2, xa3, xb0, xb1, xb2, xb3);                           \
    __builtin_amdgcn_s_setprio(0);                                            \
    LK0;                                                                      \
    VMSTMT;                                                                   \
    BARSTMT;                                                                  \
    /* second half: read kk0(t+1) -> X, MFMA kk1 with Y (independent) */      \
    if (RDNEXT) {                                                             \
        READ_A(xa0, xa1, xa2, xa3, (BUFN));                                   \
        READ_B(xb0, xb1, xb2, xb3, (BUFN) + 16384);                           \
    }                                                                         \
    __builtin_amdgcn_s_setprio(1);                                            \
    MFMA16(ya0, ya1, ya2, ya3, yb0, yb1, yb2, yb3);                           \
    __builtin_amdgcn_s_setprio(0);                                            \
} while (0)

    // prologue: stage tiles 0,1; wait tile 0 (tile 1's 6 stay flying);
    // pre-read kk0(0) frags into X
    STAGE6(0, Ld);
    STAGE6(1, Ld + 24576);
    VM6;
    SBAR;
    READ_A(xa0, xa1, xa2, xa3, Ld);
    READ_B(xb0, xb1, xb2, xb3, Ld + 16384);

    // phases 0..20 (7 groups of 3); cur = t%3
    for (int t = 0; t < 21; t += 3) {
        PH(Ld,             Ld + 24576,     STAGE6(t + 2, Ld + 2 * 24576), VM6, SBAR, 1);
        PH(Ld + 24576,     Ld + 2 * 24576, STAGE6(t + 3, Ld),             VM6, SBAR, 1);
        PH(Ld + 2 * 24576, Ld,             STAGE6(t + 4, Ld + 24576),     VM6, SBAR, 1);
    }
    // phase 21 (cur buf0): stages tile 23 -> buf2
    PH(Ld,             Ld + 24576,     STAGE6(23, Ld + 2 * 24576), VM6, SBAR, 1);
    // phase 22 (cur buf1): no stage; need tile 23 fully in -> vmcnt(0)
    PH(Ld + 24576,     Ld + 2 * 24576, NOPS,                       VM0, SBAR, 1);
    // phase 23 (cur buf2): last tile, no next
    PH(Ld + 2 * 24576, Ld,             NOPS,                       NOPS, NOPS, 0);

#undef PH
#undef MFMA16
#undef READ_A
#undef READ_B
#undef STAGE6

    // epilogue: fused argmin. col = brow + wc*64 + n*16 + lo16
    int coln[4]; float cnv[4];
#pragma unroll
    for (int n = 0; n < 4; ++n) {
        coln[n] = brow + wc * 64 + n * 16 + lo16;
        cnv[n] = cnorm[coln[n]];
    }
#pragma unroll
    for (int m = 0; m < 4; ++m) {
#pragma unroll
        for (int j = 0; j < 4; ++j) {
            unsigned long long best = 0xFFFFFFFFFFFFFFFFull;
#pragma unroll
            for (int n = 0; n < 4; ++n) {
                float d = fmaf(-2.0f, acc[m][n][j], cnv[n]);
                unsigned u = __float_as_uint(d);
                u = (u & 0x80000000u) ? ~u : (u | 0x80000000u);   // order-preserving map
                unsigned long long pk = ((unsigned long long)u << 32) | (unsigned)coln[n];
                best = pk < best ? pk : best;
            }
#pragma unroll
            for (int mask = 1; mask <= 8; mask <<= 1) {
                unsigned long long o = __shfl_xor(best, mask, 64);
                best = o < best ? o : best;
            }
            if (lo16 == 0) {
                const int row = arow + wr * 64 + m * 16 + hi4 * 4 + j;
                atomicMin(&packed[row], best);
            }
        }
    }
}

// ---------------------------------------------------------------------------
// gather (packed): z_q write, out_idx write, vq_loss accumulate
// ---------------------------------------------------------------------------
__global__ __launch_bounds__(256, 2)
void vq_gather_packed_kernel(const float* __restrict__ cb, const float* __restrict__ z,
                             const unsigned long long* __restrict__ packed,
                             float* __restrict__ out_zq, float* __restrict__ out_idx,
                             float* __restrict__ loss)
{
    __shared__ float rows[64 * 257];
    __shared__ int   ks[64];
    __shared__ float wsum[4];

    const int t   = threadIdx.x;
    const int blk = blockIdx.x;            // 512 blocks
    const int b   = blk >> 4;
    const int hw0 = (blk & 15) << 6;
    const int n0  = blk << 6;

    if (t < 64) {
        const int k = (int)(packed[n0 + t] & 0xFFFFFFFFull);
        ks[t] = k;
        out_idx[n0 + t] = (float)k;
    }
    __syncthreads();

#pragma unroll 4
    for (int i = 0; i < 64; ++i) {
        rows[i * 257 + t] = cb[(size_t)ks[i] * 256 + t];
    }
    __syncthreads();

    const int dq = t >> 6;
    const int hw = t & 63;
    const size_t obase = ((size_t)b << 18) + hw0 + hw;
    float sum = 0.f;
#pragma unroll 4
    for (int dd = 0; dd < 64; ++dd) {
        const int d = (dq << 6) + dd;
        const float  q  = rows[hw * 257 + d];
        const size_t a  = obase + (size_t)d * 1024;
        const float  zv = z[a];
        out_zq[a] = q;
        const float diff = q - zv;
        sum = fmaf(diff, diff, sum);
    }
#pragma unroll
    for (int m = 1; m <= 32; m <<= 1) sum += __shfl_xor(sum, m, 64);
    if ((t & 63) == 0) wsum[t >> 6] = sum;
    __syncthreads();
    if (t == 0) {
        const float s = (wsum[0] + wsum[1]) + (wsum[2] + wsum[3]);
        atomicAdd(loss, s * (1.25f / 8388608.0f));   // (1+0.25)*SSE/(B*D*H*W)
    }
}

// ===========================================================================
// FALLBACK PATH (ws too small): round-3 fp32 VALU kernels, known-passing.
// ===========================================================================
__global__ __launch_bounds__(256)
void vq_transpose_kernel(const float* __restrict__ cb, float* __restrict__ ctT)
{
    __shared__ float tile[64 * 65];
    const int t  = threadIdx.x;
    const int kb = blockIdx.x >> 2, db = blockIdx.x & 3;
    const int k0 = kb << 6, d0 = db << 6;
#pragma unroll
    for (int i = 0; i < 16; ++i) {
        int idx = i * 256 + t;
        int r = idx >> 6, c = idx & 63;
        tile[r * 65 + c] = cb[(size_t)(k0 + r) * 256 + d0 + c];
    }
    __syncthreads();
#pragma unroll
    for (int i = 0; i < 16; ++i) {
        int idx = i * 256 + t;
        int r = idx >> 6, c = idx & 63;
        ctT[(size_t)(d0 + r) * 1024 + k0 + c] = tile[c * 65 + r];
    }
}

__global__ __launch_bounds__(256)
void vq_cnorm_fb_kernel(const float* __restrict__ cb, float* __restrict__ cnorm)
{
    const int k = blockIdx.x * 256 + threadIdx.x;  // grid=4
    const float4* row = reinterpret_cast<const float4*>(cb + (size_t)k * 256);
    float s0 = 0.f, s1 = 0.f, s2 = 0.f, s3 = 0.f;
#pragma unroll 8
    for (int i = 0; i < 64; ++i) {
        float4 v = row[i];
        s0 = fmaf(v.x, v.x, s0);
        s1 = fmaf(v.y, v.y, s1);
        s2 = fmaf(v.z, v.z, s2);
        s3 = fmaf(v.w, v.w, s3);
    }
    cnorm[k] = (s0 + s1) + (s2 + s3);
}

__global__ __launch_bounds__(512, 2)
void vq_argmin_kernel(const float* __restrict__ z, const float* __restrict__ ctT,
                      const float* __restrict__ cnorm, int* __restrict__ codes,
                      float* __restrict__ out_idx)
{
    __shared__ float zt[256 * 64];
    __shared__ float ct[16 * 256];
    const int t = threadIdx.x, tx = t & 63, ty = t >> 6, p0 = ty << 3;
    const int blk = blockIdx.x, b = blk >> 4, hw0 = (blk & 15) << 6;
    const float* zbase = z + ((size_t)b << 18) + hw0;
#pragma unroll
    for (int i = 0; i < 8; ++i) {
        int idx = i * 512 + t;
        int d = idx >> 4, c4 = (idx & 15) << 2;
        float4 v = *reinterpret_cast<const float4*>(zbase + (size_t)d * 1024 + c4);
        *reinterpret_cast<float4*>(&zt[d * 64 + c4]) = v;
    }
    float minv[8]; int mini[8];
#pragma unroll
    for (int i = 0; i < 8; ++i) { minv[i] = 3.0e38f; mini[i] = 0; }
    const float* zrd = &zt[p0];
    const float* crd = &ct[tx << 2];
    for (int kt = 0; kt < 4; ++kt) {
        const int k0 = kt << 8;
        float acc[8][4];
#pragma unroll
        for (int i = 0; i < 8; ++i)
#pragma unroll
            for (int j = 0; j < 4; ++j) acc[i][j] = 0.f;
        for (int dc = 0; dc < 16; ++dc) {
            const int d0 = dc << 4;
            __syncthreads();
#pragma unroll
            for (int i = 0; i < 2; ++i) {
                int idx = i * 512 + t;
                int r = idx >> 6, c4 = (idx & 63) << 2;
                float4 v = *reinterpret_cast<const float4*>(ctT + (size_t)(d0 + r) * 1024 + k0 + c4);
                *reinterpret_cast<float4*>(&ct[r * 256 + c4]) = v;
            }
            __syncthreads();
            const float* zp = zrd + d0 * 64;
#pragma unroll
            for (int d = 0; d < 16; ++d) {
                float4 za = *reinterpret_cast<const float4*>(zp + d * 64);
                float4 zb = *reinterpret_cast<const float4*>(zp + d * 64 + 4);
                float4 cc = *reinterpret_cast<const float4*>(crd + d * 256);
#define VQ_FMA_ROW(ii, zv)                          \
                acc[ii][0] = fmaf(zv, cc.x, acc[ii][0]); \
                acc[ii][1] = fmaf(zv, cc.y, acc[ii][1]); \
                acc[ii][2] = fmaf(zv, cc.z, acc[ii][2]); \
                acc[ii][3] = fmaf(zv, cc.w, acc[ii][3]);
                VQ_FMA_ROW(0, za.x) VQ_FMA_ROW(1, za.y) VQ_FMA_ROW(2, za.z) VQ_FMA_ROW(3, za.w)
                VQ_FMA_ROW(4, zb.x) VQ_FMA_ROW(5, zb.y) VQ_FMA_ROW(6, zb.z) VQ_FMA_ROW(7, zb.w)
#undef VQ_FMA_ROW
            }
        }
#pragma unroll
        for (int j = 0; j < 4; ++j) {
            const int k = k0 + (tx << 2) + j;
            const float cn = cnorm[k];
#pragma unroll
            for (int i = 0; i < 8; ++i) {
                float dist = fmaf(-2.0f, acc[i][j], cn);
                if (dist < minv[i]) { minv[i] = dist; mini[i] = k; }
            }
        }
    }
#pragma unroll
    for (int m = 1; m <= 32; m <<= 1) {
#pragma unroll
        for (int i = 0; i < 8; ++i) {
            float ov = __shfl_xor(minv[i], m, 64);
            int   oi = __shfl_xor(mini[i], m, 64);
            if (ov < minv[i] || (ov == minv[i] && oi < mini[i])) { minv[i] = ov; mini[i] = oi; }
        }
    }
    if (tx == 0) {
        const int n0 = (blk << 6) + p0;
#pragma unroll
        for (int i = 0; i < 8; ++i) {
            codes[n0 + i]   = mini[i];
            out_idx[n0 + i] = (float)mini[i];
        }
    }
}

__global__ __launch_bounds__(256, 2)
void vq_gather_kernel(const float* __restrict__ cb, const float* __restrict__ z,
                      const int* __restrict__ codes, float* __restrict__ out_zq,
                      float* __restrict__ loss)
{
    __shared__ float rows[64 * 257];
    __shared__ int   ks[64];
    __shared__ float wsum[4];
    const int t = threadIdx.x, blk = blockIdx.x;
    const int b = blk >> 4, hw0 = (blk & 15) << 6, n0 = blk << 6;
    if (t < 64) ks[t] = codes[n0 + t];
    __syncthreads();
#pragma unroll 4
    for (int i = 0; i < 64; ++i) rows[i * 257 + t] = cb[(size_t)ks[i] * 256 + t];
    __syncthreads();
    const int dq = t >> 6, hw = t & 63;
    const size_t obase = ((size_t)b << 18) + hw0 + hw;
    float sum = 0.f;
#pragma unroll 4
    for (int dd = 0; dd < 64; ++dd) {
        const int d = (dq << 6) + dd;
        const float  q  = rows[hw * 257 + d];
        const size_t a  = obase + (size_t)d * 1024;
        const float  zv = z[a];
        out_zq[a] = q;
        const float diff = q - zv;
        sum = fmaf(diff, diff, sum);
    }
#pragma unroll
    for (int m = 1; m <= 32; m <<= 1) sum += __shfl_xor(sum, m, 64);
    if ((t & 63) == 0) wsum[t >> 6] = sum;
    __syncthreads();
    if (t == 0) {
        const float s = (wsum[0] + wsum[1]) + (wsum[2] + wsum[3]);
        atomicAdd(loss, s * (1.25f / 8388608.0f));
    }
}

// ---------------------------------------------------------------------------
extern "C" void kernel_launch(void* const* d_in, const int* in_sizes, int n_in,
                              void* d_out, int out_size, void* d_ws, size_t ws_size,
                              hipStream_t stream)
{
    (void)in_sizes; (void)n_in; (void)out_size;

    const float* z  = (const float*)d_in[0];   // 32*256*32*32 fp32
    const float* cb = (const float*)d_in[1];   // 1024*256 fp32

    float* out      = (float*)d_out;
    float* out_zq   = out;                     // 8388608
    float* out_idx  = out + 8388608;           // 32768 (indices as float values)
    float* out_loss = out + 8421376;           // 1

    // MFMA-path workspace: packed(256KB) | z0|z1|z2 (16MB each) | c0|c1|c2 | cnorm
    const size_t NEED = 262144ull + 3ull * 16777216ull + 3ull * 524288ull + 4096ull;

    if (ws_size >= NEED) {
        unsigned long long* packed = (unsigned long long*)d_ws;
        unsigned short* z0 = (unsigned short*)((char*)d_ws + 262144);
        unsigned short* z1 = z0 + 8388608u;
        unsigned short* z2 = z1 + 8388608u;
        unsigned short* c0 = z2 + 8388608u;
        unsigned short* c1 = c0 + 262144u;
        unsigned short* c2 = c1 + 262144u;
        float* cnorm = (float*)(c2 + 262144u);

        vq_csplit_kernel<<<256, 256, 0, stream>>>(cb, c0, c1, c2, packed, out_loss);
        vq_cnorm_kernel<<<4, 256, 0, stream>>>(cb, cnorm);
        vq_zsplit_kernel<<<512, 256, 0, stream>>>(z, z0, z1, z2);
        vq_mfma_argmin_kernel<<<1024, 512, 0, stream>>>(z0, c0, cnorm, packed);
        vq_gather_packed_kernel<<<512, 256, 0, stream>>>(cb, z, packed, out_zq, out_idx, out_loss);
    } else {
        // fallback: round-3 fp32 path (ws >= 1.38MB known OK)
        float* ctT   = (float*)d_ws;
        float* cnorm = ctT + 256 * 1024;
        int*   codes = (int*)(cnorm + 1024);

        hipMemsetAsync(out_loss, 0, sizeof(float), stream);
        vq_transpose_kernel<<<64, 256, 0, stream>>>(cb, ctT);
        vq_cnorm_fb_kernel<<<4, 256, 0, stream>>>(cb, cnorm);
        vq_argmin_kernel<<<512, 512, 0, stream>>>(z, ctT, cnorm, codes, out_idx);
        vq_gather_kernel<<<512, 256, 0, stream>>>(cb, z, codes, out_zq, out_loss);
    }
}